// Round 7
// baseline (392.839 us; speedup 1.0000x reference)
//
#include <hip/hip_runtime.h>
#include <stdint.h>

#define DIM   1024
#define INTER 2048
#define NEXP  8

typedef _Float16 f16;
typedef __attribute__((ext_vector_type(4))) _Float16 f16x4;
typedef __attribute__((ext_vector_type(8))) _Float16 f16x8;
typedef __attribute__((ext_vector_type(4))) float    f32x4;

// ---------------- async global->LDS (16B per lane) ----------------
static __device__ __forceinline__ void gload16(const void* gsrc, void* lds) {
    __builtin_amdgcn_global_load_lds(
        (const __attribute__((address_space(1))) uint32_t*)gsrc,
        (__attribute__((address_space(3))) uint32_t*)lds,
        16, 0, 0);
}

// ---------------- fused gate (sigmoid top-2) + x fp32->fp16 conversion ----------------
__global__ void gate_convert_kernel(const float* __restrict__ x, const float* __restrict__ Wg,
                                    f16* __restrict__ xh, float* __restrict__ gw,
                                    int* __restrict__ gidx, int T) {
    const int tok  = (int)((blockIdx.x * (size_t)blockDim.x + threadIdx.x) >> 6);
    const int lane = threadIdx.x & 63;
    if (tok >= T) return;
    const float4* xr  = (const float4*)(x + (size_t)tok * DIM);
    f16*          xhr = xh + (size_t)tok * DIM;
    float s[NEXP];
    #pragma unroll
    for (int e = 0; e < NEXP; ++e) s[e] = 0.f;
    #pragma unroll
    for (int it = 0; it < 4; ++it) {
        int i = it * 64 + lane;
        float4 xv = xr[i];
        f16x4 hv = { (f16)xv.x, (f16)xv.y, (f16)xv.z, (f16)xv.w };
        *(f16x4*)(xhr + i * 4) = hv;
        #pragma unroll
        for (int e = 0; e < NEXP; ++e) {
            float4 wv = ((const float4*)(Wg + e * DIM))[i];
            s[e] += xv.x * wv.x + xv.y * wv.y + xv.z * wv.z + xv.w * wv.w;
        }
    }
    #pragma unroll
    for (int e = 0; e < NEXP; ++e) {
        #pragma unroll
        for (int off = 32; off > 0; off >>= 1) s[e] += __shfl_xor(s[e], off);
    }
    if (lane == 0) {
        float sc[NEXP];
        #pragma unroll
        for (int e = 0; e < NEXP; ++e) sc[e] = 1.f / (1.f + expf(-s[e]));
        int i0 = 0;
        #pragma unroll
        for (int e = 1; e < NEXP; ++e) if (sc[e] > sc[i0]) i0 = e;
        int i1 = -1;
        #pragma unroll
        for (int e = 0; e < NEXP; ++e) if (e != i0 && (i1 < 0 || sc[e] > sc[i1])) i1 = e;
        float w0 = sc[i0], w1 = sc[i1];
        float inv = 1.f / (w0 + w1);
        gw[2 * tok + 0] = w0 * inv;
        gw[2 * tok + 1] = w1 * inv;
        gidx[2 * tok + 0] = i0;
        gidx[2 * tok + 1] = i1;
    }
}

// ---------------- W[e][K][N] fp32 -> Wt[e][N][K] fp16 (LDS-tiled transpose) ----------------
__global__ void transpose_conv_kernel(const float* __restrict__ W, f16* __restrict__ Wt, int K, int N) {
    __shared__ f16 tile[64][65];
    const int e  = blockIdx.z;
    const int kb = blockIdx.y * 64;
    const int nb = blockIdx.x * 64;
    const int tx = threadIdx.x & 63;
    const int ty = threadIdx.x >> 6;
    const float* We  = W  + (size_t)e * K * N;
    f16*         Wte = Wt + (size_t)e * K * N;
    #pragma unroll
    for (int i = 0; i < 16; ++i) {
        int k = ty + i * 4;
        tile[k][tx] = (f16)We[(size_t)(kb + k) * N + nb + tx];
    }
    __syncthreads();
    #pragma unroll
    for (int i = 0; i < 16; ++i) {
        int n = ty + i * 4;
        Wte[(size_t)(nb + n) * K + kb + tx] = tile[tx][n];
    }
}

// ---------------- routing: histogram + scan + deterministic rank scatter, ONE block, no atomics ----------------
__global__ __launch_bounds__(1024)
void route_kernel(const int* __restrict__ gidx, int* __restrict__ offsets,
                  int* __restrict__ tor, int* __restrict__ ros, int T) {
    const int tid  = threadIdx.x;
    const int lane = tid & 63;
    const int wv   = tid >> 6;
    const int NE   = 2 * T;
    __shared__ int wc[16][NEXP];
    __shared__ int rb[NEXP];

    int c[NEXP];
    #pragma unroll
    for (int e = 0; e < NEXP; ++e) c[e] = 0;
    for (int i = tid; i < NE; i += 1024) {
        int g = gidx[i];
        #pragma unroll
        for (int e = 0; e < NEXP; ++e) c[e] += (g == e) ? 1 : 0;
    }
    #pragma unroll
    for (int e = 0; e < NEXP; ++e) {
        #pragma unroll
        for (int off = 32; off > 0; off >>= 1) c[e] += __shfl_xor(c[e], off);
    }
    if (lane == 0) {
        #pragma unroll
        for (int e = 0; e < NEXP; ++e) wc[wv][e] = c[e];
    }
    __syncthreads();
    if (tid == 0) {
        int acc = 0;
        for (int e = 0; e < NEXP; ++e) {
            int t = 0;
            for (int w2 = 0; w2 < 16; ++w2) t += wc[w2][e];
            offsets[e] = acc;
            rb[e] = acc;
            acc += t;
        }
        offsets[NEXP] = acc;
    }
    __syncthreads();

    for (int base = 0; base < NE; base += 1024) {
        int i = base + tid;
        int g = gidx[i];
        int myrank = 0;
        #pragma unroll
        for (int e = 0; e < NEXP; ++e) {
            unsigned long long m = __ballot(g == e);
            if (g == e) myrank = __popcll(m & ((1ull << lane) - 1ull));
            if (lane == 0) wc[wv][e] = __popcll(m);
        }
        __syncthreads();
        int pre = 0;
        for (int w2 = 0; w2 < wv; ++w2) pre += wc[w2][g];
        int pos = rb[g] + pre + myrank;
        tor[pos] = i >> 1;
        ros[i]   = pos;
        __syncthreads();
        if (tid < NEXP) {
            int t = 0;
            for (int w2 = 0; w2 < 16; ++w2) t += wc[w2][tid];
            rb[tid] += t;
        }
        __syncthreads();
    }
}

// ---------------- grouped GEMM: 256x256 tile, 8 waves (2Mx4N), K-half-phased schedule ----------------
// BK=64 K-tiles, 2 dbufs, each split into TWO K-HALVES (ks=0: k 0-31, ks=1: k 32-63),
// LDS [dbuf][ks][256 rows x 32 k] (128 KiB total). 4 phases per tile:
//   P0: readB(ks0)+readA(ks0,mq0) | stage KA1(t+1) | bar | MFMA(mq0) | bar
//   P1: readA(ks0,mq1)            | stage KB1(t+1) | bar | MFMA(mq1) | vmcnt(8) bar
//   P2: readB(ks1)+readA(ks1,mq0) | stage KA0(t+2) | bar | MFMA(mq0) | bar
//   P3: readA(ks1,mq1)            | stage KB0(t+2) | bar | MFMA(mq1) | vmcnt(8) bar
// Every waited-on half-stage has >=5 phases of slack (vs 1 phase in the R6 port);
// vmcnt counted (8 = 4 newer half-stages x 2 loads), never 0 except at the tail.
// ks0 region of a dbuf is last read at P1, ks1 at P3 => the stage stream above
// never writes a region that can still be read (each dangerous boundary carries
// the vmcnt asm w/ memory clobber + barrier). Swizzle (proven 0-conflict):
// 16B slot' = slot ^ ((row>>1)&3) within each 64B half-row, applied on the
// global source (linear LDS dest) and the ds_read address.
// Balanced 4x2 XCD banding: xcd = (rt&3)*2 + (nt&1).
template<int KD, int ND, bool RELU, bool GATHER, int RT>
__global__ __launch_bounds__(512)
void moe_gemm_kernel(const f16* __restrict__ Abase, const f16* __restrict__ Bt,
                     const float* __restrict__ bias, const int* __restrict__ offsets,
                     const int* __restrict__ tok, f16* __restrict__ Cout) {
    constexpr int NT  = ND / 256;
    constexpr int NT2 = NT / 2;
    constexpr int RT4 = RT / 4;
    const int bid = blockIdx.x;
    const int xcd = bid & 7;
    const int j   = bid >> 3;
    const int nt  = (j % NT2) * 2 + (xcd & 1);
    const int rt  = ((j / NT2) % RT4) * 4 + (xcd >> 1);
    const int e   = j / (NT2 * RT4);

    const int rowBeg = offsets[e];
    const int rowEnd = offsets[e + 1];
    const int row0   = rowBeg + rt * 256;
    if (row0 >= rowEnd) return;
    const int n0   = nt * 256;
    const int tid  = threadIdx.x;
    const int lane = tid & 63;
    const int wid  = tid >> 6;
    const int wm   = wid >> 2;          // 2 m-wave groups (128 rows each)
    const int wn   = wid & 3;           // 4 n-wave groups (64 cols each)

    __shared__ __align__(16) f16 As[2][2][256 * 32];   // [dbuf][ks]
    __shared__ __align__(16) f16 Bs[2][2][256 * 32];

    const f16* Bte = Bt + (size_t)e * ND * KD;

    // staging: chunk c = i*512+tid; row=c>>2 (0..255), slot=c&3, kc = slot^((row>>1)&3)
    size_t aOff[2], bOff[2];
    int ldsOff[2];
    #pragma unroll
    for (int i = 0; i < 2; ++i) {
        int c  = i * 512 + tid;
        int r  = c >> 2;
        int kc = (c & 3) ^ ((r >> 1) & 3);
        ldsOff[i] = c * 8;
        int gr = row0 + r;
        if (gr >= rowEnd) gr = rowEnd - 1;
        int ar = GATHER ? tok[gr] : gr;
        aOff[i] = (size_t)ar * KD + kc * 8;
        bOff[i] = (size_t)(n0 + r) * KD + kc * 8;
    }

    auto stageA = [&](int d, int ks, int kt) {
        #pragma unroll
        for (int i = 0; i < 2; ++i)
            gload16(Abase + aOff[i] + kt * 64 + ks * 32, &As[d][ks][ldsOff[i]]);
    };
    auto stageB = [&](int d, int ks, int kt) {
        #pragma unroll
        for (int i = 0; i < 2; ++i)
            gload16(Bte + bOff[i] + kt * 64 + ks * 32, &Bs[d][ks][ldsOff[i]]);
    };

    f32x4 acc[8][4] = {};
    f16x8 af[4], bf0[4], bf1[4];

    const int rb  = lane & 15;
    const int sl8 = ((lane >> 4) ^ ((lane >> 1) & 3)) * 8;

    auto readA = [&](int d, int ks, int mq) {
        const f16* base = &As[d][ks][0];
        #pragma unroll
        for (int m = 0; m < 4; ++m)
            af[m] = *(const f16x8*)&base[(wm * 128 + mq * 64 + m * 16 + rb) * 32 + sl8];
    };
    auto readB = [&](int d, int ks, f16x8 (&bf)[4]) {
        const f16* base = &Bs[d][ks][0];
        #pragma unroll
        for (int n = 0; n < 4; ++n)
            bf[n] = *(const f16x8*)&base[(wn * 64 + n * 16 + rb) * 32 + sl8];
    };
    auto mfma16 = [&](int mq, f16x8 (&bf)[4]) {
        #pragma unroll
        for (int m = 0; m < 4; ++m)
            #pragma unroll
            for (int n = 0; n < 4; ++n)
                acc[mq * 4 + m][n] = __builtin_amdgcn_mfma_f32_16x16x32_f16(
                    af[m], bf[n], acc[mq * 4 + m][n], 0, 0, 0);
    };

    constexpr int nK = KD / 64;   // 16 or 32

    // prologue stream: KA0(0),KB0(0),KA1(0),KB1(0),KA0(1),KB0(1)
    stageA(0, 0, 0); stageB(0, 0, 0);
    stageA(0, 1, 0); stageB(0, 1, 0);
    stageA(1, 0, 1); stageB(1, 0, 1);
    asm volatile("s_waitcnt vmcnt(8)" ::: "memory");   // KA0(0),KB0(0) done
    __builtin_amdgcn_s_barrier();

    for (int t = 0; t < nK; ++t) {
        const int d = t & 1;
        // ---- P0: ks0, mq0 ----
        readB(d, 0, bf0);
        readA(d, 0, 0);
        if (t + 1 < nK) stageA(d ^ 1, 1, t + 1);       // KA1(t+1)
        __builtin_amdgcn_s_barrier();
        __builtin_amdgcn_s_setprio(1);
        mfma16(0, bf0);
        __builtin_amdgcn_s_setprio(0);
        __builtin_amdgcn_s_barrier();
        // ---- P1: ks0, mq1 ----
        readA(d, 0, 1);
        if (t + 1 < nK) stageB(d ^ 1, 1, t + 1);       // KB1(t+1)
        __builtin_amdgcn_s_barrier();
        __builtin_amdgcn_s_setprio(1);
        mfma16(1, bf0);
        __builtin_amdgcn_s_setprio(0);
        if (t + 1 < nK) { asm volatile("s_waitcnt vmcnt(8)" ::: "memory"); }  // KA1/KB1(t) done
        else            { asm volatile("s_waitcnt vmcnt(0)" ::: "memory"); }
        __builtin_amdgcn_s_barrier();
        // ---- P2: ks1, mq0 ----
        readB(d, 1, bf1);
        readA(d, 1, 0);
        if (t + 2 < nK) stageA(d, 0, t + 2);           // KA0(t+2)
        __builtin_amdgcn_s_barrier();
        __builtin_amdgcn_s_setprio(1);
        mfma16(0, bf1);
        __builtin_amdgcn_s_setprio(0);
        __builtin_amdgcn_s_barrier();
        // ---- P3: ks1, mq1 ----
        readA(d, 1, 1);
        if (t + 2 < nK) stageB(d, 0, t + 2);           // KB0(t+2)
        __builtin_amdgcn_s_barrier();
        __builtin_amdgcn_s_setprio(1);
        mfma16(1, bf1);
        __builtin_amdgcn_s_setprio(0);
        if (t + 2 < nK)      { asm volatile("s_waitcnt vmcnt(8)" ::: "memory"); }  // KA0/KB0(t+1) done
        else if (t + 1 < nK) { asm volatile("s_waitcnt vmcnt(4)" ::: "memory"); }
        __builtin_amdgcn_s_barrier();
    }
    asm volatile("s_waitcnt vmcnt(0)" ::: "memory");

    const int rowsValid = rowEnd - row0;
    const int wr  = wm * 128;
    const int wcn = wn * 64;
    #pragma unroll
    for (int m = 0; m < 8; ++m) {
        #pragma unroll
        for (int n = 0; n < 4; ++n) {
            #pragma unroll
            for (int j2 = 0; j2 < 4; ++j2) {
                int rl  = wr + m * 16 + ((lane >> 4) << 2) + j2;
                int col = n0 + wcn + n * 16 + (lane & 15);
                if (rl < rowsValid) {
                    float v = acc[m][n][j2] + bias[e * ND + col];
                    if (RELU) v = fmaxf(v, 0.f);
                    Cout[(size_t)(row0 + rl) * ND + col] = (f16)v;
                }
            }
        }
    }
}

// ---------------- combine: y[t] = w0*eo[r0] + w1*eo[r1] ----------------
__global__ void combine_kernel(const f16* __restrict__ eo, const int* __restrict__ ros,
                               const float* __restrict__ gw, float* __restrict__ y, int T) {
    int gid = blockIdx.x * 256 + threadIdx.x;
    int t   = gid >> 7;
    if (t >= T) return;
    int c0 = (gid & 127) * 8;
    int r0 = ros[2 * t], r1 = ros[2 * t + 1];
    float w0 = gw[2 * t], w1 = gw[2 * t + 1];
    f16x8 v0 = *(const f16x8*)(eo + (size_t)r0 * DIM + c0);
    f16x8 v1 = *(const f16x8*)(eo + (size_t)r1 * DIM + c0);
    f32x4 o0, o1;
    #pragma unroll
    for (int j = 0; j < 4; ++j) o0[j] = w0 * (float)v0[j] + w1 * (float)v1[j];
    #pragma unroll
    for (int j = 0; j < 4; ++j) o1[j] = w0 * (float)v0[4 + j] + w1 * (float)v1[4 + j];
    *(f32x4*)(y + (size_t)t * DIM + c0)     = o0;
    *(f32x4*)(y + (size_t)t * DIM + c0 + 4) = o1;
}

extern "C" void kernel_launch(void* const* d_in, const int* in_sizes, int n_in,
                              void* d_out, int out_size, void* d_ws, size_t ws_size,
                              hipStream_t stream) {
    const float* x  = (const float*)d_in[0];
    const float* Wg = (const float*)d_in[1];
    const float* W1 = (const float*)d_in[2];
    const float* b1 = (const float*)d_in[3];
    const float* W2 = (const float*)d_in[4];
    const float* b2 = (const float*)d_in[5];
    float* y = (float*)d_out;
    const int T = in_sizes[0] / DIM;   // 8192

    char* ws = (char*)d_ws;
    size_t off = 0;
    auto alloc = [&](size_t bytes) -> char* {
        char* p = ws + off;
        off += (bytes + 255) & ~(size_t)255;
        return p;
    };
    f16* xh   = (f16*)alloc((size_t)T * DIM * 2);
    f16* w1t  = (f16*)alloc((size_t)NEXP * DIM * INTER * 2);
    f16* w2t  = (f16*)alloc((size_t)NEXP * DIM * INTER * 2);
    f16* h    = (f16*)alloc((size_t)2 * T * INTER * 2);
    f16* eo   = (f16*)alloc((size_t)2 * T * DIM * 2);
    float* gw = (float*)alloc((size_t)T * 2 * 4);
    int* gidx = (int*)alloc((size_t)T * 2 * 4);
    int* ros  = (int*)alloc((size_t)T * 2 * 4);
    int* tor  = (int*)alloc((size_t)2 * T * 4);
    int* offsets = (int*)alloc(64 * 4);

    gate_convert_kernel<<<T / 4, 256, 0, stream>>>(x, Wg, xh, gw, gidx, T);
    transpose_conv_kernel<<<dim3(INTER / 64, DIM / 64, NEXP), 256, 0, stream>>>(W1, w1t, DIM, INTER);
    transpose_conv_kernel<<<dim3(DIM / 64, INTER / 64, NEXP), 256, 0, stream>>>(W2, w2t, INTER, DIM);
    route_kernel<<<1, 1024, 0, stream>>>(gidx, offsets, tor, ros, T);
    // RT = 32: expert max rows = T = 8192 = 32 tiles of 256
    moe_gemm_kernel<DIM, INTER, true, true, 32>
        <<<dim3(((INTER / 256) / 2) * (32 / 4) * NEXP * 8), 512, 0, stream>>>(xh, w1t, b1, offsets, tor, h);
    moe_gemm_kernel<INTER, DIM, false, false, 32>
        <<<dim3(((DIM / 256) / 2) * (32 / 4) * NEXP * 8), 512, 0, stream>>>(h, w2t, b2, offsets, tor, eo);
    combine_kernel<<<(T * DIM / 8 + 255) / 256, 256, 0, stream>>>(eo, ros, gw, y, T);
}

// Round 8
// 350.171 us; speedup vs baseline: 1.1218x; 1.1218x over previous
//
#include <hip/hip_runtime.h>
#include <stdint.h>

#define DIM   1024
#define INTER 2048
#define NEXP  8

typedef _Float16 f16;
typedef __attribute__((ext_vector_type(4))) _Float16 f16x4;
typedef __attribute__((ext_vector_type(8))) _Float16 f16x8;
typedef __attribute__((ext_vector_type(4))) float    f32x4;

// ---------------- async global->LDS (16B per lane) ----------------
static __device__ __forceinline__ void gload16(const void* gsrc, void* lds) {
    __builtin_amdgcn_global_load_lds(
        (const __attribute__((address_space(1))) uint32_t*)gsrc,
        (__attribute__((address_space(3))) uint32_t*)lds,
        16, 0, 0);
}

// ---------------- fused gate (sigmoid top-2) + x fp32->fp16 conversion ----------------
__global__ void gate_convert_kernel(const float* __restrict__ x, const float* __restrict__ Wg,
                                    f16* __restrict__ xh, float* __restrict__ gw,
                                    int* __restrict__ gidx, int T) {
    const int tok  = (int)((blockIdx.x * (size_t)blockDim.x + threadIdx.x) >> 6);
    const int lane = threadIdx.x & 63;
    if (tok >= T) return;
    const float4* xr  = (const float4*)(x + (size_t)tok * DIM);
    f16*          xhr = xh + (size_t)tok * DIM;
    float s[NEXP];
    #pragma unroll
    for (int e = 0; e < NEXP; ++e) s[e] = 0.f;
    #pragma unroll
    for (int it = 0; it < 4; ++it) {
        int i = it * 64 + lane;
        float4 xv = xr[i];
        f16x4 hv = { (f16)xv.x, (f16)xv.y, (f16)xv.z, (f16)xv.w };
        *(f16x4*)(xhr + i * 4) = hv;
        #pragma unroll
        for (int e = 0; e < NEXP; ++e) {
            float4 wv = ((const float4*)(Wg + e * DIM))[i];
            s[e] += xv.x * wv.x + xv.y * wv.y + xv.z * wv.z + xv.w * wv.w;
        }
    }
    #pragma unroll
    for (int e = 0; e < NEXP; ++e) {
        #pragma unroll
        for (int off = 32; off > 0; off >>= 1) s[e] += __shfl_xor(s[e], off);
    }
    if (lane == 0) {
        float sc[NEXP];
        #pragma unroll
        for (int e = 0; e < NEXP; ++e) sc[e] = 1.f / (1.f + expf(-s[e]));
        int i0 = 0;
        #pragma unroll
        for (int e = 1; e < NEXP; ++e) if (sc[e] > sc[i0]) i0 = e;
        int i1 = -1;
        #pragma unroll
        for (int e = 0; e < NEXP; ++e) if (e != i0 && (i1 < 0 || sc[e] > sc[i1])) i1 = e;
        float w0 = sc[i0], w1 = sc[i1];
        float inv = 1.f / (w0 + w1);
        gw[2 * tok + 0] = w0 * inv;
        gw[2 * tok + 1] = w1 * inv;
        gidx[2 * tok + 0] = i0;
        gidx[2 * tok + 1] = i1;
    }
}

// ---------------- W[e][K][N] fp32 -> Wt[e][N][K] fp16 (LDS-tiled transpose) ----------------
__global__ void transpose_conv_kernel(const float* __restrict__ W, f16* __restrict__ Wt, int K, int N) {
    __shared__ f16 tile[64][65];
    const int e  = blockIdx.z;
    const int kb = blockIdx.y * 64;
    const int nb = blockIdx.x * 64;
    const int tx = threadIdx.x & 63;
    const int ty = threadIdx.x >> 6;
    const float* We  = W  + (size_t)e * K * N;
    f16*         Wte = Wt + (size_t)e * K * N;
    #pragma unroll
    for (int i = 0; i < 16; ++i) {
        int k = ty + i * 4;
        tile[k][tx] = (f16)We[(size_t)(kb + k) * N + nb + tx];
    }
    __syncthreads();
    #pragma unroll
    for (int i = 0; i < 16; ++i) {
        int n = ty + i * 4;
        Wte[(size_t)(nb + n) * K + kb + tx] = tile[tx][n];
    }
}

// ---------------- routing: histogram + scan + deterministic rank scatter, ONE block, no atomics ----------------
__global__ __launch_bounds__(1024)
void route_kernel(const int* __restrict__ gidx, int* __restrict__ offsets,
                  int* __restrict__ tor, int* __restrict__ ros, int T) {
    const int tid  = threadIdx.x;
    const int lane = tid & 63;
    const int wv   = tid >> 6;
    const int NE   = 2 * T;
    __shared__ int wc[16][NEXP];
    __shared__ int rb[NEXP];

    int c[NEXP];
    #pragma unroll
    for (int e = 0; e < NEXP; ++e) c[e] = 0;
    for (int i = tid; i < NE; i += 1024) {
        int g = gidx[i];
        #pragma unroll
        for (int e = 0; e < NEXP; ++e) c[e] += (g == e) ? 1 : 0;
    }
    #pragma unroll
    for (int e = 0; e < NEXP; ++e) {
        #pragma unroll
        for (int off = 32; off > 0; off >>= 1) c[e] += __shfl_xor(c[e], off);
    }
    if (lane == 0) {
        #pragma unroll
        for (int e = 0; e < NEXP; ++e) wc[wv][e] = c[e];
    }
    __syncthreads();
    if (tid == 0) {
        int acc = 0;
        for (int e = 0; e < NEXP; ++e) {
            int t = 0;
            for (int w2 = 0; w2 < 16; ++w2) t += wc[w2][e];
            offsets[e] = acc;
            rb[e] = acc;
            acc += t;
        }
        offsets[NEXP] = acc;
    }
    __syncthreads();

    for (int base = 0; base < NE; base += 1024) {
        int i = base + tid;
        int g = gidx[i];
        int myrank = 0;
        #pragma unroll
        for (int e = 0; e < NEXP; ++e) {
            unsigned long long m = __ballot(g == e);
            if (g == e) myrank = __popcll(m & ((1ull << lane) - 1ull));
            if (lane == 0) wc[wv][e] = __popcll(m);
        }
        __syncthreads();
        int pre = 0;
        for (int w2 = 0; w2 < wv; ++w2) pre += wc[w2][g];
        int pos = rb[g] + pre + myrank;
        tor[pos] = i >> 1;
        ros[i]   = pos;
        __syncthreads();
        if (tid < NEXP) {
            int t = 0;
            for (int w2 = 0; w2 < 16; ++w2) t += wc[w2][tid];
            rb[tid] += t;
        }
        __syncthreads();
    }
}

// ---------------- grouped GEMM: 128x128 tile, 4 waves, T3 minimal 2-phase pipeline ----------------
// BK=32, double-buffered LDS (32 KiB total => ~5 blocks/CU resident; implicit
// inter-block overlap hides the per-step drain, m97/m114 regime). Per K-step:
// issue next tile's 4 gload16 FIRST, then ds_read+MFMA current, then ONE
// __syncthreads (vmcnt drain at the end => HBM latency hides under compute).
// LDS 16B-slot swizzle slot' = slot ^ ((row>>1)&3) (proven 0-conflict, R3/R4),
// applied on the global-source side (linear LDS dest) and the ds_read side.
// Balanced 4x2 XCD banding: xcd = (rt&3)*2 + (nt&1) (proven fetch x2 cut, R4).
template<int KD, int ND, bool RELU, bool GATHER, int RT>
__global__ __launch_bounds__(256)
void moe_gemm_kernel(const f16* __restrict__ Abase, const f16* __restrict__ Bt,
                     const float* __restrict__ bias, const int* __restrict__ offsets,
                     const int* __restrict__ tok, f16* __restrict__ Cout) {
    constexpr int NT  = ND / 128;
    constexpr int NT2 = NT / 2;
    constexpr int RT4 = RT / 4;
    const int bid = blockIdx.x;
    const int xcd = bid & 7;
    const int j   = bid >> 3;
    const int nt  = (j % NT2) * 2 + (xcd & 1);
    const int rt  = ((j / NT2) % RT4) * 4 + (xcd >> 1);
    const int e   = j / (NT2 * RT4);

    const int rowBeg = offsets[e];
    const int rowEnd = offsets[e + 1];
    const int row0   = rowBeg + rt * 128;
    if (row0 >= rowEnd) return;
    const int n0   = nt * 128;
    const int tid  = threadIdx.x;
    const int lane = tid & 63;
    const int wid  = tid >> 6;
    const int wr   = (wid >> 1) * 64;
    const int wc   = (wid & 1) * 64;

    __shared__ __align__(16) f16 As[2][128 * 32];
    __shared__ __align__(16) f16 Bs[2][128 * 32];

    const f16* Bte = Bt + (size_t)e * ND * KD;

    // staging: chunk c = i*256+tid; row = c>>2, slot = c&3, kc = slot^((row>>1)&3)
    const f16* Aptr[2];
    const f16* Bptr[2];
    int ldsOff[2];
    #pragma unroll
    for (int i = 0; i < 2; ++i) {
        int c  = i * 256 + tid;
        int r  = c >> 2;
        int kc = (c & 3) ^ ((c >> 3) & 3);
        ldsOff[i] = c * 8;
        int gr = row0 + r;
        if (gr >= rowEnd) gr = rowEnd - 1;
        int ar = GATHER ? tok[gr] : gr;
        Aptr[i] = Abase + (size_t)ar * KD + kc * 8;
        Bptr[i] = Bte + (size_t)(n0 + r) * KD + kc * 8;
    }

    auto stage = [&](int buf, int kt) {
        const int k0 = kt * 32;
        #pragma unroll
        for (int i = 0; i < 2; ++i)
            gload16(Aptr[i] + k0, &As[buf][ldsOff[i]]);
        #pragma unroll
        for (int i = 0; i < 2; ++i)
            gload16(Bptr[i] + k0, &Bs[buf][ldsOff[i]]);
    };

    f32x4 acc[4][4] = {};

    // swizzled read slot: (lane>>4) ^ ((row>>1)&3); row bits 0-3 == lane&15
    const int sl = ((lane >> 4) ^ ((lane >> 1) & 3)) * 8;
    const int rb = lane & 15;

    constexpr int nK = KD / 32;
    stage(0, 0);
    __syncthreads();

    int cur = 0;
    for (int kt = 0; kt < nK; ++kt) {
        if (kt + 1 < nK) stage(cur ^ 1, kt + 1);   // issue next tile BEFORE compute

        const f16* Asb = As[cur];
        const f16* Bsb = Bs[cur];
        f16x8 af[4], bfr[4];
        #pragma unroll
        for (int m = 0; m < 4; ++m)
            af[m] = *(const f16x8*)&Asb[(wr + m * 16 + rb) * 32 + sl];
        #pragma unroll
        for (int n = 0; n < 4; ++n)
            bfr[n] = *(const f16x8*)&Bsb[(wc + n * 16 + rb) * 32 + sl];
        __builtin_amdgcn_s_setprio(1);
        #pragma unroll
        for (int m = 0; m < 4; ++m)
            #pragma unroll
            for (int n = 0; n < 4; ++n)
                acc[m][n] = __builtin_amdgcn_mfma_f32_16x16x32_f16(af[m], bfr[n], acc[m][n], 0, 0, 0);
        __builtin_amdgcn_s_setprio(0);

        __syncthreads();                           // single drain: next tile ready
        cur ^= 1;
    }

    const int rowsValid = rowEnd - row0;
    #pragma unroll
    for (int m = 0; m < 4; ++m) {
        #pragma unroll
        for (int n = 0; n < 4; ++n) {
            #pragma unroll
            for (int j2 = 0; j2 < 4; ++j2) {
                int rl  = wr + m * 16 + ((lane >> 4) << 2) + j2;
                int col = n0 + wc + n * 16 + (lane & 15);
                if (rl < rowsValid) {
                    float v = acc[m][n][j2] + bias[e * ND + col];
                    if (RELU) v = fmaxf(v, 0.f);
                    Cout[(size_t)(row0 + rl) * ND + col] = (f16)v;
                }
            }
        }
    }
}

// ---------------- combine: y[t] = w0*eo[r0] + w1*eo[r1] ----------------
__global__ void combine_kernel(const f16* __restrict__ eo, const int* __restrict__ ros,
                               const float* __restrict__ gw, float* __restrict__ y, int T) {
    int gid = blockIdx.x * 256 + threadIdx.x;
    int t   = gid >> 7;
    if (t >= T) return;
    int c0 = (gid & 127) * 8;
    int r0 = ros[2 * t], r1 = ros[2 * t + 1];
    float w0 = gw[2 * t], w1 = gw[2 * t + 1];
    f16x8 v0 = *(const f16x8*)(eo + (size_t)r0 * DIM + c0);
    f16x8 v1 = *(const f16x8*)(eo + (size_t)r1 * DIM + c0);
    f32x4 o0, o1;
    #pragma unroll
    for (int j = 0; j < 4; ++j) o0[j] = w0 * (float)v0[j] + w1 * (float)v1[j];
    #pragma unroll
    for (int j = 0; j < 4; ++j) o1[j] = w0 * (float)v0[4 + j] + w1 * (float)v1[4 + j];
    *(f32x4*)(y + (size_t)t * DIM + c0)     = o0;
    *(f32x4*)(y + (size_t)t * DIM + c0 + 4) = o1;
}

extern "C" void kernel_launch(void* const* d_in, const int* in_sizes, int n_in,
                              void* d_out, int out_size, void* d_ws, size_t ws_size,
                              hipStream_t stream) {
    const float* x  = (const float*)d_in[0];
    const float* Wg = (const float*)d_in[1];
    const float* W1 = (const float*)d_in[2];
    const float* b1 = (const float*)d_in[3];
    const float* W2 = (const float*)d_in[4];
    const float* b2 = (const float*)d_in[5];
    float* y = (float*)d_out;
    const int T = in_sizes[0] / DIM;   // 8192

    char* ws = (char*)d_ws;
    size_t off = 0;
    auto alloc = [&](size_t bytes) -> char* {
        char* p = ws + off;
        off += (bytes + 255) & ~(size_t)255;
        return p;
    };
    f16* xh   = (f16*)alloc((size_t)T * DIM * 2);
    f16* w1t  = (f16*)alloc((size_t)NEXP * DIM * INTER * 2);
    f16* w2t  = (f16*)alloc((size_t)NEXP * DIM * INTER * 2);
    f16* h    = (f16*)alloc((size_t)2 * T * INTER * 2);
    f16* eo   = (f16*)alloc((size_t)2 * T * DIM * 2);
    float* gw = (float*)alloc((size_t)T * 2 * 4);
    int* gidx = (int*)alloc((size_t)T * 2 * 4);
    int* ros  = (int*)alloc((size_t)T * 2 * 4);
    int* tor  = (int*)alloc((size_t)2 * T * 4);
    int* offsets = (int*)alloc(64 * 4);

    gate_convert_kernel<<<T / 4, 256, 0, stream>>>(x, Wg, xh, gw, gidx, T);
    transpose_conv_kernel<<<dim3(INTER / 64, DIM / 64, NEXP), 256, 0, stream>>>(W1, w1t, DIM, INTER);
    transpose_conv_kernel<<<dim3(DIM / 64, INTER / 64, NEXP), 256, 0, stream>>>(W2, w2t, INTER, DIM);
    route_kernel<<<1, 1024, 0, stream>>>(gidx, offsets, tor, ros, T);
    // RT = 64: expert max rows = T = 8192 = 64 tiles of 128
    moe_gemm_kernel<DIM, INTER, true, true, 64>
        <<<dim3(((INTER / 128) / 2) * (64 / 4) * NEXP * 8), 256, 0, stream>>>(xh, w1t, b1, offsets, tor, h);
    moe_gemm_kernel<INTER, DIM, false, false, 64>
        <<<dim3(((DIM / 128) / 2) * (64 / 4) * NEXP * 8), 256, 0, stream>>>(h, w2t, b2, offsets, tor, eo);
    combine_kernel<<<(T * DIM / 8 + 255) / 256, 256, 0, stream>>>(eo, ros, gw, y, T);
}

// Round 9
// 336.600 us; speedup vs baseline: 1.1671x; 1.0403x over previous
//
#include <hip/hip_runtime.h>
#include <stdint.h>

#define DIM   1024
#define INTER 2048
#define NEXP  8

typedef _Float16 f16;
typedef __attribute__((ext_vector_type(4))) _Float16 f16x4;
typedef __attribute__((ext_vector_type(8))) _Float16 f16x8;
typedef __attribute__((ext_vector_type(4))) float    f32x4;

// ---------------- async global->LDS (16B per lane) ----------------
static __device__ __forceinline__ void gload16(const void* gsrc, void* lds) {
    __builtin_amdgcn_global_load_lds(
        (const __attribute__((address_space(1))) uint32_t*)gsrc,
        (__attribute__((address_space(3))) uint32_t*)lds,
        16, 0, 0);
}

// ---------------- fused gate (sigmoid top-2) + x fp32->fp16 conversion ----------------
__global__ void gate_convert_kernel(const float* __restrict__ x, const float* __restrict__ Wg,
                                    f16* __restrict__ xh, float* __restrict__ gw,
                                    int* __restrict__ gidx, int T) {
    const int tok  = (int)((blockIdx.x * (size_t)blockDim.x + threadIdx.x) >> 6);
    const int lane = threadIdx.x & 63;
    if (tok >= T) return;
    const float4* xr  = (const float4*)(x + (size_t)tok * DIM);
    f16*          xhr = xh + (size_t)tok * DIM;
    float s[NEXP];
    #pragma unroll
    for (int e = 0; e < NEXP; ++e) s[e] = 0.f;
    #pragma unroll
    for (int it = 0; it < 4; ++it) {
        int i = it * 64 + lane;
        float4 xv = xr[i];
        f16x4 hv = { (f16)xv.x, (f16)xv.y, (f16)xv.z, (f16)xv.w };
        *(f16x4*)(xhr + i * 4) = hv;
        #pragma unroll
        for (int e = 0; e < NEXP; ++e) {
            float4 wv = ((const float4*)(Wg + e * DIM))[i];
            s[e] += xv.x * wv.x + xv.y * wv.y + xv.z * wv.z + xv.w * wv.w;
        }
    }
    #pragma unroll
    for (int e = 0; e < NEXP; ++e) {
        #pragma unroll
        for (int off = 32; off > 0; off >>= 1) s[e] += __shfl_xor(s[e], off);
    }
    if (lane == 0) {
        float sc[NEXP];
        #pragma unroll
        for (int e = 0; e < NEXP; ++e) sc[e] = 1.f / (1.f + expf(-s[e]));
        int i0 = 0;
        #pragma unroll
        for (int e = 1; e < NEXP; ++e) if (sc[e] > sc[i0]) i0 = e;
        int i1 = -1;
        #pragma unroll
        for (int e = 0; e < NEXP; ++e) if (e != i0 && (i1 < 0 || sc[e] > sc[i1])) i1 = e;
        float w0 = sc[i0], w1 = sc[i1];
        float inv = 1.f / (w0 + w1);
        gw[2 * tok + 0] = w0 * inv;
        gw[2 * tok + 1] = w1 * inv;
        gidx[2 * tok + 0] = i0;
        gidx[2 * tok + 1] = i1;
    }
}

// ---------------- W[e][K][N] fp32 -> Wt[e][N][K] fp16 (LDS-tiled transpose) ----------------
__global__ void transpose_conv_kernel(const float* __restrict__ W, f16* __restrict__ Wt, int K, int N) {
    __shared__ f16 tile[64][65];
    const int e  = blockIdx.z;
    const int kb = blockIdx.y * 64;
    const int nb = blockIdx.x * 64;
    const int tx = threadIdx.x & 63;
    const int ty = threadIdx.x >> 6;
    const float* We  = W  + (size_t)e * K * N;
    f16*         Wte = Wt + (size_t)e * K * N;
    #pragma unroll
    for (int i = 0; i < 16; ++i) {
        int k = ty + i * 4;
        tile[k][tx] = (f16)We[(size_t)(kb + k) * N + nb + tx];
    }
    __syncthreads();
    #pragma unroll
    for (int i = 0; i < 16; ++i) {
        int n = ty + i * 4;
        Wte[(size_t)(nb + n) * K + kb + tx] = tile[tx][n];
    }
}

// ---------------- routing: histogram + scan + deterministic rank scatter, ONE block, no atomics ----------------
__global__ __launch_bounds__(1024)
void route_kernel(const int* __restrict__ gidx, int* __restrict__ offsets,
                  int* __restrict__ tor, int* __restrict__ ros, int T) {
    const int tid  = threadIdx.x;
    const int lane = tid & 63;
    const int wv   = tid >> 6;
    const int NE   = 2 * T;
    __shared__ int wc[16][NEXP];
    __shared__ int rb[NEXP];

    int c[NEXP];
    #pragma unroll
    for (int e = 0; e < NEXP; ++e) c[e] = 0;
    for (int i = tid; i < NE; i += 1024) {
        int g = gidx[i];
        #pragma unroll
        for (int e = 0; e < NEXP; ++e) c[e] += (g == e) ? 1 : 0;
    }
    #pragma unroll
    for (int e = 0; e < NEXP; ++e) {
        #pragma unroll
        for (int off = 32; off > 0; off >>= 1) c[e] += __shfl_xor(c[e], off);
    }
    if (lane == 0) {
        #pragma unroll
        for (int e = 0; e < NEXP; ++e) wc[wv][e] = c[e];
    }
    __syncthreads();
    if (tid == 0) {
        int acc = 0;
        for (int e = 0; e < NEXP; ++e) {
            int t = 0;
            for (int w2 = 0; w2 < 16; ++w2) t += wc[w2][e];
            offsets[e] = acc;
            rb[e] = acc;
            acc += t;
        }
        offsets[NEXP] = acc;
    }
    __syncthreads();

    for (int base = 0; base < NE; base += 1024) {
        int i = base + tid;
        int g = gidx[i];
        int myrank = 0;
        #pragma unroll
        for (int e = 0; e < NEXP; ++e) {
            unsigned long long m = __ballot(g == e);
            if (g == e) myrank = __popcll(m & ((1ull << lane) - 1ull));
            if (lane == 0) wc[wv][e] = __popcll(m);
        }
        __syncthreads();
        int pre = 0;
        for (int w2 = 0; w2 < wv; ++w2) pre += wc[w2][g];
        int pos = rb[g] + pre + myrank;
        tor[pos] = i >> 1;
        ros[i]   = pos;
        __syncthreads();
        if (tid < NEXP) {
            int t = 0;
            for (int w2 = 0; w2 < 16; ++w2) t += wc[w2][tid];
            rb[tid] += t;
        }
        __syncthreads();
    }
}

// ---------------- grouped GEMM: 128x128 tile, 4 waves, m97-style SINGLE-buffered loop ----------------
// BK=32, ONE 16 KiB A-tile + ONE 16 KiB B-tile (32 KiB total => LDS allows 10
// blocks/CU; wave cap 8 blocks/CU = 32 waves). Loop: stage(kt) -> sync ->
// ds_read+MFMA -> sync. Intra-block overlap is sacrificed; cross-block TLP
// (m114/m97 regime: many resident blocks at different phases) hides the
// stage latency and LDS-read latency. No setprio (null on lockstep GEMM, m190).
// LDS 16B-slot swizzle slot' = slot ^ ((row>>1)&3) (proven 0-conflict),
// applied on the global-source side (linear LDS dest) and the ds_read side.
// Balanced 4x2 XCD banding: xcd = (rt&3)*2 + (nt&1) (proven fetch cut, R4).
template<int KD, int ND, bool RELU, bool GATHER, int RT>
__global__ __launch_bounds__(256)
void moe_gemm_kernel(const f16* __restrict__ Abase, const f16* __restrict__ Bt,
                     const float* __restrict__ bias, const int* __restrict__ offsets,
                     const int* __restrict__ tok, f16* __restrict__ Cout) {
    constexpr int NT  = ND / 128;
    constexpr int NT2 = NT / 2;
    constexpr int RT4 = RT / 4;
    const int bid = blockIdx.x;
    const int xcd = bid & 7;
    const int j   = bid >> 3;
    const int nt  = (j % NT2) * 2 + (xcd & 1);
    const int rt  = ((j / NT2) % RT4) * 4 + (xcd >> 1);
    const int e   = j / (NT2 * RT4);

    const int rowBeg = offsets[e];
    const int rowEnd = offsets[e + 1];
    const int row0   = rowBeg + rt * 128;
    if (row0 >= rowEnd) return;
    const int n0   = nt * 128;
    const int tid  = threadIdx.x;
    const int lane = tid & 63;
    const int wid  = tid >> 6;
    const int wr   = (wid >> 1) * 64;
    const int wc   = (wid & 1) * 64;

    __shared__ __align__(16) f16 As[128 * 32];
    __shared__ __align__(16) f16 Bs[128 * 32];

    const f16* Bte = Bt + (size_t)e * ND * KD;

    // staging: chunk c = i*256+tid; row = c>>2, slot = c&3, kc = slot^((row>>1)&3)
    const f16* Aptr[2];
    const f16* Bptr[2];
    int ldsOff[2];
    #pragma unroll
    for (int i = 0; i < 2; ++i) {
        int c  = i * 256 + tid;
        int r  = c >> 2;
        int kc = (c & 3) ^ ((c >> 3) & 3);
        ldsOff[i] = c * 8;
        int gr = row0 + r;
        if (gr >= rowEnd) gr = rowEnd - 1;
        int ar = GATHER ? tok[gr] : gr;
        Aptr[i] = Abase + (size_t)ar * KD + kc * 8;
        Bptr[i] = Bte + (size_t)(n0 + r) * KD + kc * 8;
    }

    f32x4 acc[4][4] = {};

    // swizzled read slot: (lane>>4) ^ ((row>>1)&3); row bits 0-3 == lane&15
    const int sl = ((lane >> 4) ^ ((lane >> 1) & 3)) * 8;
    const int rb = lane & 15;

    constexpr int nK = KD / 32;
    for (int kt = 0; kt < nK; ++kt) {
        const int k0 = kt * 32;
        #pragma unroll
        for (int i = 0; i < 2; ++i)
            gload16(Aptr[i] + k0, &As[ldsOff[i]]);
        #pragma unroll
        for (int i = 0; i < 2; ++i)
            gload16(Bptr[i] + k0, &Bs[ldsOff[i]]);
        __syncthreads();                       // drains vmcnt: tile ready

        f16x8 af[4], bfr[4];
        #pragma unroll
        for (int m = 0; m < 4; ++m)
            af[m] = *(const f16x8*)&As[(wr + m * 16 + rb) * 32 + sl];
        #pragma unroll
        for (int n = 0; n < 4; ++n)
            bfr[n] = *(const f16x8*)&Bs[(wc + n * 16 + rb) * 32 + sl];
        #pragma unroll
        for (int m = 0; m < 4; ++m)
            #pragma unroll
            for (int n = 0; n < 4; ++n)
                acc[m][n] = __builtin_amdgcn_mfma_f32_16x16x32_f16(af[m], bfr[n], acc[m][n], 0, 0, 0);

        __syncthreads();                       // all reads done before next stage overwrites
    }

    const int rowsValid = rowEnd - row0;
    #pragma unroll
    for (int m = 0; m < 4; ++m) {
        #pragma unroll
        for (int n = 0; n < 4; ++n) {
            #pragma unroll
            for (int j2 = 0; j2 < 4; ++j2) {
                int rl  = wr + m * 16 + ((lane >> 4) << 2) + j2;
                int col = n0 + wc + n * 16 + (lane & 15);
                if (rl < rowsValid) {
                    float v = acc[m][n][j2] + bias[e * ND + col];
                    if (RELU) v = fmaxf(v, 0.f);
                    Cout[(size_t)(row0 + rl) * ND + col] = (f16)v;
                }
            }
        }
    }
}

// ---------------- combine: y[t] = w0*eo[r0] + w1*eo[r1] ----------------
__global__ void combine_kernel(const f16* __restrict__ eo, const int* __restrict__ ros,
                               const float* __restrict__ gw, float* __restrict__ y, int T) {
    int gid = blockIdx.x * 256 + threadIdx.x;
    int t   = gid >> 7;
    if (t >= T) return;
    int c0 = (gid & 127) * 8;
    int r0 = ros[2 * t], r1 = ros[2 * t + 1];
    float w0 = gw[2 * t], w1 = gw[2 * t + 1];
    f16x8 v0 = *(const f16x8*)(eo + (size_t)r0 * DIM + c0);
    f16x8 v1 = *(const f16x8*)(eo + (size_t)r1 * DIM + c0);
    f32x4 o0, o1;
    #pragma unroll
    for (int j = 0; j < 4; ++j) o0[j] = w0 * (float)v0[j] + w1 * (float)v1[j];
    #pragma unroll
    for (int j = 0; j < 4; ++j) o1[j] = w0 * (float)v0[4 + j] + w1 * (float)v1[4 + j];
    *(f32x4*)(y + (size_t)t * DIM + c0)     = o0;
    *(f32x4*)(y + (size_t)t * DIM + c0 + 4) = o1;
}

extern "C" void kernel_launch(void* const* d_in, const int* in_sizes, int n_in,
                              void* d_out, int out_size, void* d_ws, size_t ws_size,
                              hipStream_t stream) {
    const float* x  = (const float*)d_in[0];
    const float* Wg = (const float*)d_in[1];
    const float* W1 = (const float*)d_in[2];
    const float* b1 = (const float*)d_in[3];
    const float* W2 = (const float*)d_in[4];
    const float* b2 = (const float*)d_in[5];
    float* y = (float*)d_out;
    const int T = in_sizes[0] / DIM;   // 8192

    char* ws = (char*)d_ws;
    size_t off = 0;
    auto alloc = [&](size_t bytes) -> char* {
        char* p = ws + off;
        off += (bytes + 255) & ~(size_t)255;
        return p;
    };
    f16* xh   = (f16*)alloc((size_t)T * DIM * 2);
    f16* w1t  = (f16*)alloc((size_t)NEXP * DIM * INTER * 2);
    f16* w2t  = (f16*)alloc((size_t)NEXP * DIM * INTER * 2);
    f16* h    = (f16*)alloc((size_t)2 * T * INTER * 2);
    f16* eo   = (f16*)alloc((size_t)2 * T * DIM * 2);
    float* gw = (float*)alloc((size_t)T * 2 * 4);
    int* gidx = (int*)alloc((size_t)T * 2 * 4);
    int* ros  = (int*)alloc((size_t)T * 2 * 4);
    int* tor  = (int*)alloc((size_t)2 * T * 4);
    int* offsets = (int*)alloc(64 * 4);

    gate_convert_kernel<<<T / 4, 256, 0, stream>>>(x, Wg, xh, gw, gidx, T);
    transpose_conv_kernel<<<dim3(INTER / 64, DIM / 64, NEXP), 256, 0, stream>>>(W1, w1t, DIM, INTER);
    transpose_conv_kernel<<<dim3(DIM / 64, INTER / 64, NEXP), 256, 0, stream>>>(W2, w2t, INTER, DIM);
    route_kernel<<<1, 1024, 0, stream>>>(gidx, offsets, tor, ros, T);
    // RT = 64: expert max rows = T = 8192 = 64 tiles of 128
    moe_gemm_kernel<DIM, INTER, true, true, 64>
        <<<dim3(((INTER / 128) / 2) * (64 / 4) * NEXP * 8), 256, 0, stream>>>(xh, w1t, b1, offsets, tor, h);
    moe_gemm_kernel<INTER, DIM, false, false, 64>
        <<<dim3(((DIM / 128) / 2) * (64 / 4) * NEXP * 8), 256, 0, stream>>>(h, w2t, b2, offsets, tor, eo);
    combine_kernel<<<(T * DIM / 8 + 255) / 256, 256, 0, stream>>>(eo, ros, gw, y, T);
}

// Round 10
// 329.842 us; speedup vs baseline: 1.1910x; 1.0205x over previous
//
#include <hip/hip_runtime.h>
#include <stdint.h>

#define DIM   1024
#define INTER 2048
#define NEXP  8

typedef _Float16 f16;
typedef __attribute__((ext_vector_type(4))) _Float16 f16x4;
typedef __attribute__((ext_vector_type(8))) _Float16 f16x8;
typedef __attribute__((ext_vector_type(4))) float    f32x4;

// ---------------- async global->LDS (16B per lane) ----------------
static __device__ __forceinline__ void gload16(const void* gsrc, void* lds) {
    __builtin_amdgcn_global_load_lds(
        (const __attribute__((address_space(1))) uint32_t*)gsrc,
        (__attribute__((address_space(3))) uint32_t*)lds,
        16, 0, 0);
}

// ---------------- fused gate (sigmoid top-2) + x fp32->fp16 conversion ----------------
__global__ void gate_convert_kernel(const float* __restrict__ x, const float* __restrict__ Wg,
                                    f16* __restrict__ xh, float* __restrict__ gw,
                                    int* __restrict__ gidx, int T) {
    const int tok  = (int)((blockIdx.x * (size_t)blockDim.x + threadIdx.x) >> 6);
    const int lane = threadIdx.x & 63;
    if (tok >= T) return;
    const float4* xr  = (const float4*)(x + (size_t)tok * DIM);
    f16*          xhr = xh + (size_t)tok * DIM;
    float s[NEXP];
    #pragma unroll
    for (int e = 0; e < NEXP; ++e) s[e] = 0.f;
    #pragma unroll
    for (int it = 0; it < 4; ++it) {
        int i = it * 64 + lane;
        float4 xv = xr[i];
        f16x4 hv = { (f16)xv.x, (f16)xv.y, (f16)xv.z, (f16)xv.w };
        *(f16x4*)(xhr + i * 4) = hv;
        #pragma unroll
        for (int e = 0; e < NEXP; ++e) {
            float4 wv = ((const float4*)(Wg + e * DIM))[i];
            s[e] += xv.x * wv.x + xv.y * wv.y + xv.z * wv.z + xv.w * wv.w;
        }
    }
    #pragma unroll
    for (int e = 0; e < NEXP; ++e) {
        #pragma unroll
        for (int off = 32; off > 0; off >>= 1) s[e] += __shfl_xor(s[e], off);
    }
    if (lane == 0) {
        float sc[NEXP];
        #pragma unroll
        for (int e = 0; e < NEXP; ++e) sc[e] = 1.f / (1.f + expf(-s[e]));
        int i0 = 0;
        #pragma unroll
        for (int e = 1; e < NEXP; ++e) if (sc[e] > sc[i0]) i0 = e;
        int i1 = -1;
        #pragma unroll
        for (int e = 0; e < NEXP; ++e) if (e != i0 && (i1 < 0 || sc[e] > sc[i1])) i1 = e;
        float w0 = sc[i0], w1 = sc[i1];
        float inv = 1.f / (w0 + w1);
        gw[2 * tok + 0] = w0 * inv;
        gw[2 * tok + 1] = w1 * inv;
        gidx[2 * tok + 0] = i0;
        gidx[2 * tok + 1] = i1;
    }
}

// ---------------- W[e][K][N] fp32 -> Wt[e][N][K] fp16 (LDS-tiled transpose) ----------------
__global__ void transpose_conv_kernel(const float* __restrict__ W, f16* __restrict__ Wt, int K, int N) {
    __shared__ f16 tile[64][65];
    const int e  = blockIdx.z;
    const int kb = blockIdx.y * 64;
    const int nb = blockIdx.x * 64;
    const int tx = threadIdx.x & 63;
    const int ty = threadIdx.x >> 6;
    const float* We  = W  + (size_t)e * K * N;
    f16*         Wte = Wt + (size_t)e * K * N;
    #pragma unroll
    for (int i = 0; i < 16; ++i) {
        int k = ty + i * 4;
        tile[k][tx] = (f16)We[(size_t)(kb + k) * N + nb + tx];
    }
    __syncthreads();
    #pragma unroll
    for (int i = 0; i < 16; ++i) {
        int n = ty + i * 4;
        Wte[(size_t)(nb + n) * K + kb + tx] = tile[tx][n];
    }
}

// ---------------- routing: histogram + scan + deterministic rank scatter, ONE block, no atomics ----------------
__global__ __launch_bounds__(1024)
void route_kernel(const int* __restrict__ gidx, int* __restrict__ offsets,
                  int* __restrict__ tor, int* __restrict__ ros, int T) {
    const int tid  = threadIdx.x;
    const int lane = tid & 63;
    const int wv   = tid >> 6;
    const int NE   = 2 * T;
    __shared__ int wc[16][NEXP];
    __shared__ int rb[NEXP];

    int c[NEXP];
    #pragma unroll
    for (int e = 0; e < NEXP; ++e) c[e] = 0;
    for (int i = tid; i < NE; i += 1024) {
        int g = gidx[i];
        #pragma unroll
        for (int e = 0; e < NEXP; ++e) c[e] += (g == e) ? 1 : 0;
    }
    #pragma unroll
    for (int e = 0; e < NEXP; ++e) {
        #pragma unroll
        for (int off = 32; off > 0; off >>= 1) c[e] += __shfl_xor(c[e], off);
    }
    if (lane == 0) {
        #pragma unroll
        for (int e = 0; e < NEXP; ++e) wc[wv][e] = c[e];
    }
    __syncthreads();
    if (tid == 0) {
        int acc = 0;
        for (int e = 0; e < NEXP; ++e) {
            int t = 0;
            for (int w2 = 0; w2 < 16; ++w2) t += wc[w2][e];
            offsets[e] = acc;
            rb[e] = acc;
            acc += t;
        }
        offsets[NEXP] = acc;
    }
    __syncthreads();

    for (int base = 0; base < NE; base += 1024) {
        int i = base + tid;
        int g = gidx[i];
        int myrank = 0;
        #pragma unroll
        for (int e = 0; e < NEXP; ++e) {
            unsigned long long m = __ballot(g == e);
            if (g == e) myrank = __popcll(m & ((1ull << lane) - 1ull));
            if (lane == 0) wc[wv][e] = __popcll(m);
        }
        __syncthreads();
        int pre = 0;
        for (int w2 = 0; w2 < wv; ++w2) pre += wc[w2][g];
        int pos = rb[g] + pre + myrank;
        tor[pos] = i >> 1;
        ros[i]   = pos;
        __syncthreads();
        if (tid < NEXP) {
            int t = 0;
            for (int w2 = 0; w2 < 16; ++w2) t += wc[w2][tid];
            rb[tid] += t;
        }
        __syncthreads();
    }
}

// ---------------- grouped GEMM: 128x128 tile, 4 waves, BK=64 single-buffered loop ----------------
// BK=64 (128 B rows): half the barriers/K-step vs BK=32; LDS 32 KiB; residency
// is VGPR-capped at 4 waves/SIMD (VGPR>64) so LDS size is free up to 40 KiB.
// Loop: stage(kt) 8x gload16 -> sync -> {ks=0: 8 ds_read_b128 + 16 MFMA,
// ks=1: same} -> sync. Frag live set stays 8 (32 VGPR) via the ks split.
// Swizzle (BK=64, 8x16B slots/row): source kc = (c&7)^(r&7); read slot =
// (ks*4 + (lane>>4)) ^ (rb&7). Bank check: lanes 0-15 span rows 0-15, slot
// j^(r&7) covers all 8 bank-quads over 8 rows -> 2-way max = free (m136).
// Balanced 4x2 XCD banding: xcd = (rt&3)*2 + (nt&1) (proven fetch cut, R4).
template<int KD, int ND, bool RELU, bool GATHER, int RT>
__global__ __launch_bounds__(256)
void moe_gemm_kernel(const f16* __restrict__ Abase, const f16* __restrict__ Bt,
                     const float* __restrict__ bias, const int* __restrict__ offsets,
                     const int* __restrict__ tok, f16* __restrict__ Cout) {
    constexpr int NT  = ND / 128;
    constexpr int NT2 = NT / 2;
    constexpr int RT4 = RT / 4;
    const int bid = blockIdx.x;
    const int xcd = bid & 7;
    const int j   = bid >> 3;
    const int nt  = (j % NT2) * 2 + (xcd & 1);
    const int rt  = ((j / NT2) % RT4) * 4 + (xcd >> 1);
    const int e   = j / (NT2 * RT4);

    const int rowBeg = offsets[e];
    const int rowEnd = offsets[e + 1];
    const int row0   = rowBeg + rt * 128;
    if (row0 >= rowEnd) return;
    const int n0   = nt * 128;
    const int tid  = threadIdx.x;
    const int lane = tid & 63;
    const int wid  = tid >> 6;
    const int wr   = (wid >> 1) * 64;
    const int wc   = (wid & 1) * 64;

    __shared__ __align__(16) f16 As[128 * 64];
    __shared__ __align__(16) f16 Bs[128 * 64];

    const f16* Bte = Bt + (size_t)e * ND * KD;

    // staging: chunk c = i*256+tid (i<4); row r = c>>3, slot = c&7, kc = slot^(r&7)
    int aOff[4], bOff[4], ldsOff[4];
    #pragma unroll
    for (int i = 0; i < 4; ++i) {
        int c  = i * 256 + tid;
        int r  = c >> 3;
        int kc = (c & 7) ^ (r & 7);
        ldsOff[i] = c * 8;
        int gr = row0 + r;
        if (gr >= rowEnd) gr = rowEnd - 1;
        int ar = GATHER ? tok[gr] : gr;
        aOff[i] = ar * KD + kc * 8;
        bOff[i] = (n0 + r) * KD + kc * 8;
    }

    f32x4 acc[4][4] = {};

    const int rb    = lane & 15;
    const int jbase = lane >> 4;     // 0..3

    constexpr int nK = KD / 64;
    for (int kt = 0; kt < nK; ++kt) {
        const int k0 = kt * 64;
        #pragma unroll
        for (int i = 0; i < 4; ++i)
            gload16(Abase + (size_t)(aOff[i] + k0), &As[ldsOff[i]]);
        #pragma unroll
        for (int i = 0; i < 4; ++i)
            gload16(Bte + (size_t)(bOff[i] + k0), &Bs[ldsOff[i]]);
        __syncthreads();                       // drains vmcnt: tile ready

        #pragma unroll
        for (int ks = 0; ks < 2; ++ks) {
            const int sl = (((ks * 4 + jbase) ^ (rb & 7))) * 8;
            f16x8 af[4], bfr[4];
            #pragma unroll
            for (int m = 0; m < 4; ++m)
                af[m] = *(const f16x8*)&As[(wr + m * 16 + rb) * 64 + sl];
            #pragma unroll
            for (int n = 0; n < 4; ++n)
                bfr[n] = *(const f16x8*)&Bs[(wc + n * 16 + rb) * 64 + sl];
            #pragma unroll
            for (int m = 0; m < 4; ++m)
                #pragma unroll
                for (int n = 0; n < 4; ++n)
                    acc[m][n] = __builtin_amdgcn_mfma_f32_16x16x32_f16(af[m], bfr[n], acc[m][n], 0, 0, 0);
        }

        __syncthreads();                       // all reads done before next stage overwrites
    }

    const int rowsValid = rowEnd - row0;
    #pragma unroll
    for (int m = 0; m < 4; ++m) {
        #pragma unroll
        for (int n = 0; n < 4; ++n) {
            #pragma unroll
            for (int j2 = 0; j2 < 4; ++j2) {
                int rl  = wr + m * 16 + ((lane >> 4) << 2) + j2;
                int col = n0 + wc + n * 16 + (lane & 15);
                if (rl < rowsValid) {
                    float v = acc[m][n][j2] + bias[e * ND + col];
                    if (RELU) v = fmaxf(v, 0.f);
                    Cout[(size_t)(row0 + rl) * ND + col] = (f16)v;
                }
            }
        }
    }
}

// ---------------- combine: y[t] = w0*eo[r0] + w1*eo[r1] ----------------
__global__ void combine_kernel(const f16* __restrict__ eo, const int* __restrict__ ros,
                               const float* __restrict__ gw, float* __restrict__ y, int T) {
    int gid = blockIdx.x * 256 + threadIdx.x;
    int t   = gid >> 7;
    if (t >= T) return;
    int c0 = (gid & 127) * 8;
    int r0 = ros[2 * t], r1 = ros[2 * t + 1];
    float w0 = gw[2 * t], w1 = gw[2 * t + 1];
    f16x8 v0 = *(const f16x8*)(eo + (size_t)r0 * DIM + c0);
    f16x8 v1 = *(const f16x8*)(eo + (size_t)r1 * DIM + c0);
    f32x4 o0, o1;
    #pragma unroll
    for (int j = 0; j < 4; ++j) o0[j] = w0 * (float)v0[j] + w1 * (float)v1[j];
    #pragma unroll
    for (int j = 0; j < 4; ++j) o1[j] = w0 * (float)v0[4 + j] + w1 * (float)v1[4 + j];
    *(f32x4*)(y + (size_t)t * DIM + c0)     = o0;
    *(f32x4*)(y + (size_t)t * DIM + c0 + 4) = o1;
}

extern "C" void kernel_launch(void* const* d_in, const int* in_sizes, int n_in,
                              void* d_out, int out_size, void* d_ws, size_t ws_size,
                              hipStream_t stream) {
    const float* x  = (const float*)d_in[0];
    const float* Wg = (const float*)d_in[1];
    const float* W1 = (const float*)d_in[2];
    const float* b1 = (const float*)d_in[3];
    const float* W2 = (const float*)d_in[4];
    const float* b2 = (const float*)d_in[5];
    float* y = (float*)d_out;
    const int T = in_sizes[0] / DIM;   // 8192

    char* ws = (char*)d_ws;
    size_t off = 0;
    auto alloc = [&](size_t bytes) -> char* {
        char* p = ws + off;
        off += (bytes + 255) & ~(size_t)255;
        return p;
    };
    f16* xh   = (f16*)alloc((size_t)T * DIM * 2);
    f16* w1t  = (f16*)alloc((size_t)NEXP * DIM * INTER * 2);
    f16* w2t  = (f16*)alloc((size_t)NEXP * DIM * INTER * 2);
    f16* h    = (f16*)alloc((size_t)2 * T * INTER * 2);
    f16* eo   = (f16*)alloc((size_t)2 * T * DIM * 2);
    float* gw = (float*)alloc((size_t)T * 2 * 4);
    int* gidx = (int*)alloc((size_t)T * 2 * 4);
    int* ros  = (int*)alloc((size_t)T * 2 * 4);
    int* tor  = (int*)alloc((size_t)2 * T * 4);
    int* offsets = (int*)alloc(64 * 4);

    gate_convert_kernel<<<T / 4, 256, 0, stream>>>(x, Wg, xh, gw, gidx, T);
    transpose_conv_kernel<<<dim3(INTER / 64, DIM / 64, NEXP), 256, 0, stream>>>(W1, w1t, DIM, INTER);
    transpose_conv_kernel<<<dim3(DIM / 64, INTER / 64, NEXP), 256, 0, stream>>>(W2, w2t, INTER, DIM);
    route_kernel<<<1, 1024, 0, stream>>>(gidx, offsets, tor, ros, T);
    // RT = 64: expert max rows = T = 8192 = 64 tiles of 128
    moe_gemm_kernel<DIM, INTER, true, true, 64>
        <<<dim3(((INTER / 128) / 2) * (64 / 4) * NEXP * 8), 256, 0, stream>>>(xh, w1t, b1, offsets, tor, h);
    moe_gemm_kernel<INTER, DIM, false, false, 64>
        <<<dim3(((DIM / 128) / 2) * (64 / 4) * NEXP * 8), 256, 0, stream>>>(h, w2t, b2, offsets, tor, eo);
    combine_kernel<<<(T * DIM / 8 + 255) / 256, 256, 0, stream>>>(eo, ros, gw, y, T);
}